// Round 8
// baseline (50.273 us; speedup 1.0000x reference)
//
#include <hip/hip_runtime.h>

typedef short bf16x8 __attribute__((ext_vector_type(8)));
typedef float f32x16 __attribute__((ext_vector_type(16)));

static constexpr int KH = 15, KW = 15;
static constexpr int HI = 4096, WI = 4096;
static constexpr int HO = HI - KH + 1, WO = WI - KW + 1;   // 4082 x 4082
static constexpr int TM = 128, TN = 128;                   // output tile per block
static constexpr int LR   = TM + KH - 1;                   // 142 staged rows
static constexpr int LC   = 144;                           // staged bf16 cols (granule max col 143)
static constexpr int LSTR = 152;                           // 304 B/row: 16B-aligned, 76 dw % 32 = 12 (benign)
static constexpr int IPR  = LC / 4;                        // 36 float4 items/row
static constexpr int ITEMS = LR * IPR;                     // 5112
static constexpr int NSLOT = 23;                           // compact B slot table (slot 22 = natural zeros)
static constexpr int BKH   = NSLOT * 8;                    // 184 shorts per kh

__device__ __forceinline__ unsigned int f2bf(float f) {
  unsigned int u = __builtin_bit_cast(unsigned int, f);
  return (u + 0x7FFFu + ((u >> 16) & 1u)) >> 16;
}

__device__ __forceinline__ unsigned int cvt_pk_bf16(float lo, float hi) {
  unsigned int r;
  asm("v_cvt_pk_bf16_f32 %0, %1, %2" : "=v"(r) : "v"(lo), "v"(hi));
  return r;
}

#define MFMA32(a, b, c) __builtin_amdgcn_mfma_f32_32x32x16_bf16((a), (b), (c), 0, 0, 0)

__global__ __launch_bounds__(256, 3)
void conv2d_w32(const float* __restrict__ x, const float* __restrict__ w,
                const float* __restrict__ bias, float* __restrict__ out) {
  __shared__ unsigned short sx[LR * LSTR];        // 43,168 B bf16 input tile
  __shared__ unsigned short btab[KH * BKH];       //  5,520 B compact sliding-window weights

  const int tid = threadIdx.x;

  // XCD-aware bijective swizzle (1024 blocks, 1024 % 8 == 0)
  const int bid0 = blockIdx.y * gridDim.x + blockIdx.x;
  const int bid  = (bid0 & 7) * 128 + (bid0 >> 3);
  const int row0 = (bid >> 5) * TM;
  const int col0 = (bid & 31) * TN;

  // ---- compact B table: btab[kh][s][t] = w[kh, s-7+t] if 0 <= s-7+t < 15 else 0
  //      (slot 22 is all-zero automatically: 22-7+t = 15+t >= 15)
  for (int i = tid; i < KH * NSLOT; i += 256) {
    const int kh = i / NSLOT;
    const int s  = i - kh * NSLOT;
    const int e0 = s - 7;
    unsigned int dw[4];
    #pragma unroll
    for (int t2 = 0; t2 < 4; ++t2) {
      const int c0 = e0 + 2 * t2;
      const int c1 = c0 + 1;
      const unsigned int b0 = (c0 >= 0 && c0 < KW) ? f2bf(w[kh * KW + c0]) : 0u;
      const unsigned int b1 = (c1 >= 0 && c1 < KW) ? f2bf(w[kh * KW + c1]) : 0u;
      dw[t2] = b0 | (b1 << 16);
    }
    *(uint4*)&btab[i * 8] = make_uint4(dw[0], dw[1], dw[2], dw[3]);
  }

  // ---- stage 142 x 144 input tile as bf16 (zero-fill OOB halo) ----
  for (int i = tid; i < ITEMS; i += 256) {
    const int r  = i / IPR;
    const int c4 = (i - r * IPR) * 4;
    const int gr = row0 + r;
    const int gc = col0 + c4;
    float4 v = make_float4(0.f, 0.f, 0.f, 0.f);
    if (gr < HI) {
      const float* p = &x[(long)gr * WI + gc];
      if (gc + 3 < WI) {
        v = *(const float4*)p;
      } else {
        if (gc + 0 < WI) v.x = p[0];
        if (gc + 1 < WI) v.y = p[1];
        if (gc + 2 < WI) v.z = p[2];
        if (gc + 3 < WI) v.w = p[3];
      }
    }
    *(uint2*)&sx[r * LSTR + c4] = make_uint2(cvt_pk_bf16(v.x, v.y), cvt_pk_bf16(v.z, v.w));
  }

  const float bs = bias[0];
  __syncthreads();

  // ---- per-wave setup: wave g = row-group (rows 32g..32g+31), all 128 cols (4 tiles) ----
  const int lane = tid & 63;
  const int g    = tid >> 6;
  const int n    = lane & 31;                 // A row-lane / B col / out col within tile
  const int kg   = lane >> 5;                 // k-group: k = 8*kg + t

  // A granule u (u=0..8): x[32g + n + kh, 16u + 8kg + t]
  const unsigned short* abase = &sx[(32 * g + n) * LSTR + 8 * kg];
  // B sigma reads: slot e0 = 16*sigma + 8*kg - n, clamped to zero-slot 22
  const int e0k = 8 * kg - n;
  const int s0  = (e0k >= -7 && e0k <= 14) ? e0k + 7 : 22;
  const int s1  = (e0k >= -23 && e0k <= -2) ? e0k + 23 : 22;
  const int s2  = (e0k >= -39 && e0k <= -18) ? e0k + 39 : 22;
  const unsigned short* bb0 = &btab[s0 * 8];
  const unsigned short* bb1 = &btab[s1 * 8];
  const unsigned short* bb2 = &btab[s2 * 8];

  f32x16 acc0, acc1, acc2, acc3;
  #pragma unroll
  for (int r = 0; r < 16; ++r) { acc0[r] = bs; acc1[r] = bs; acc2[r] = bs; acc3[r] = bs; }

  // ---- main loop: per kh = 9 A-granule reads + 3 B reads + 12 MFMA, all imm-addressed ----
  __builtin_amdgcn_s_setprio(1);
  #pragma unroll
  for (int kh = 0; kh < KH; ++kh) {
    const unsigned short* ar = abase + kh * LSTR;
    bf16x8 a[9];
    #pragma unroll
    for (int u = 0; u < 9; ++u) a[u] = *(const bf16x8*)(ar + 16 * u);
    const bf16x8 b0 = *(const bf16x8*)(bb0 + kh * BKH);
    const bf16x8 b1 = *(const bf16x8*)(bb1 + kh * BKH);
    const bf16x8 b2 = *(const bf16x8*)(bb2 + kh * BKH);
    acc0 = MFMA32(a[0], b0, acc0);
    acc0 = MFMA32(a[1], b1, acc0);
    acc0 = MFMA32(a[2], b2, acc0);
    acc1 = MFMA32(a[2], b0, acc1);
    acc1 = MFMA32(a[3], b1, acc1);
    acc1 = MFMA32(a[4], b2, acc1);
    acc2 = MFMA32(a[4], b0, acc2);
    acc2 = MFMA32(a[5], b1, acc2);
    acc2 = MFMA32(a[6], b2, acc2);
    acc3 = MFMA32(a[6], b0, acc3);
    acc3 = MFMA32(a[7], b1, acc3);
    acc3 = MFMA32(a[8], b2, acc3);
  }
  __builtin_amdgcn_s_setprio(0);

  // ---- epilogue: 32x32 C/D layout col = lane&31, row = (reg&3) + 8*(reg>>2) + 4*(lane>>5) ----
  const int orb = row0 + 32 * g + 4 * kg;
  f32x16 av[4] = {acc0, acc1, acc2, acc3};
  #pragma unroll
  for (int T = 0; T < 4; ++T) {
    const int oc = col0 + 32 * T + n;
    if (oc < WO) {
      #pragma unroll
      for (int r = 0; r < 16; ++r) {
        const int orow = orb + (r & 3) + 8 * (r >> 2);
        if (orow < HO) out[(long)orow * WO + oc] = av[T][r];
      }
    }
  }
}

extern "C" void kernel_launch(void* const* d_in, const int* in_sizes, int n_in,
                              void* d_out, int out_size, void* d_ws, size_t ws_size,
                              hipStream_t stream) {
  const float* x    = (const float*)d_in[0];
  const float* w    = (const float*)d_in[1];
  const float* bias = (const float*)d_in[2];
  float* out        = (float*)d_out;

  dim3 grid(32, 32);   // 1024 blocks, 128x128 tiles
  conv2d_w32<<<grid, dim3(256, 1, 1), 0, stream>>>(x, w, bias, out);
}

// Round 9
// 44.160 us; speedup vs baseline: 1.1384x; 1.1384x over previous
//
#include <hip/hip_runtime.h>

typedef short bf16x8 __attribute__((ext_vector_type(8)));
typedef float f32x16 __attribute__((ext_vector_type(16)));

static constexpr int KH = 15, KW = 15;
static constexpr int HI = 4096, WI = 4096;
static constexpr int HO = HI - KH + 1, WO = WI - KW + 1;   // 4082 x 4082
static constexpr int TM = 128, TN = 128;                   // output tile per block
static constexpr int LR   = TM + KH - 1;                   // 142 staged rows
static constexpr int LC   = 144;                           // staged bf16 cols (granule max col 143)
static constexpr int LSTR = 152;                           // 304 B/row: 16B-aligned; benign banks (proven R6/R8)
static constexpr int IPR  = LC / 4;                        // 36 float4 items/row
static constexpr int ITEMS = LR * IPR;                     // 5112
static constexpr int NSLOT = 23;                           // compact B slot table (slot 22 = natural zeros)
static constexpr int BKH   = NSLOT * 8;                    // 184 shorts per kh

__device__ __forceinline__ unsigned int f2bf(float f) {
  unsigned int u = __builtin_bit_cast(unsigned int, f);
  return (u + 0x7FFFu + ((u >> 16) & 1u)) >> 16;
}

__device__ __forceinline__ unsigned int cvt_pk_bf16(float lo, float hi) {
  unsigned int r;
  asm("v_cvt_pk_bf16_f32 %0, %1, %2" : "=v"(r) : "v"(lo), "v"(hi));
  return r;
}

#define MFMA32(a, b, c) __builtin_amdgcn_mfma_f32_32x32x16_bf16((a), (b), (c), 0, 0, 0)

__global__ __launch_bounds__(512, 6)
void conv2d_w32b(const float* __restrict__ x, const float* __restrict__ w,
                 const float* __restrict__ bias, float* __restrict__ out) {
  __shared__ unsigned short sx[LR * LSTR];        // 43,168 B bf16 input tile
  __shared__ unsigned short btab[KH * BKH];       //  5,520 B compact sliding-window weights
  // total 48,688 B -> 3 blocks/CU, 24 waves/CU

  const int tid = threadIdx.x;

  // XCD-aware bijective swizzle (1024 blocks, 1024 % 8 == 0)
  const int bid0 = blockIdx.y * gridDim.x + blockIdx.x;
  const int bid  = (bid0 & 7) * 128 + (bid0 >> 3);
  const int row0 = (bid >> 5) * TM;
  const int col0 = (bid & 31) * TN;

  // ---- compact B table: btab[kh][s][t] = w[kh, s-7+t] if 0 <= s-7+t < 15 else 0
  //      (slot 22 is all-zero: 22-7+t = 15+t >= 15)
  for (int i = tid; i < KH * NSLOT; i += 512) {
    const int kh = i / NSLOT;
    const int s  = i - kh * NSLOT;
    const int e0 = s - 7;
    unsigned int dw[4];
    #pragma unroll
    for (int t2 = 0; t2 < 4; ++t2) {
      const int c0 = e0 + 2 * t2;
      const int c1 = c0 + 1;
      const unsigned int b0 = (c0 >= 0 && c0 < KW) ? f2bf(w[kh * KW + c0]) : 0u;
      const unsigned int b1 = (c1 >= 0 && c1 < KW) ? f2bf(w[kh * KW + c1]) : 0u;
      dw[t2] = b0 | (b1 << 16);
    }
    *(uint4*)&btab[i * 8] = make_uint4(dw[0], dw[1], dw[2], dw[3]);
  }

  // ---- stage 142 x 144 input tile as bf16 (zero-fill OOB halo) ----
  for (int i = tid; i < ITEMS; i += 512) {
    const int r  = i / IPR;
    const int c4 = (i - r * IPR) * 4;
    const int gr = row0 + r;
    const int gc = col0 + c4;
    float4 v = make_float4(0.f, 0.f, 0.f, 0.f);
    if (gr < HI) {
      const float* p = &x[(long)gr * WI + gc];
      if (gc + 3 < WI) {
        v = *(const float4*)p;
      } else {
        if (gc + 0 < WI) v.x = p[0];
        if (gc + 1 < WI) v.y = p[1];
        if (gc + 2 < WI) v.z = p[2];
        if (gc + 3 < WI) v.w = p[3];
      }
    }
    *(uint2*)&sx[r * LSTR + c4] = make_uint2(cvt_pk_bf16(v.x, v.y), cvt_pk_bf16(v.z, v.w));
  }

  const float bs = bias[0];
  __syncthreads();

  // ---- per-wave setup: wave = (row-group g = wv>>1) x (col-half p = wv&1) ----
  // wave computes out rows [32g, 32g+32) x cols [64p, 64p+64): two 32x32 tiles
  // sharing A granules (16-col slices u=0..4).
  const int lane = tid & 63;
  const int wv   = tid >> 6;
  const int g    = wv >> 1;
  const int p    = wv & 1;
  const int n    = lane & 31;                 // A row-lane / B col / out col within tile
  const int kg   = lane >> 5;                 // k-group: k = 8*kg + t

  // A granule u: x[32g + n + kh, 64p + 16u + 8kg + t]
  const unsigned short* abase = &sx[(32 * g + n) * LSTR + 64 * p + 8 * kg];
  // B sigma reads: need w[kh, e0 + t], e0 = 16*sigma + 8*kg - n; clamp to zero-slot 22
  const int e0k = 8 * kg - n;
  const int s0  = (e0k >= -7) ? e0k + 7 : 22;                      // e0k <= 8 always
  const int s1  = (e0k >= -23 && e0k <= -2) ? e0k + 23 : 22;
  const int s2  = (e0k <= -18) ? e0k + 39 : 22;                    // e0k >= -31 always
  const unsigned short* bb0 = &btab[s0 * 8];
  const unsigned short* bb1 = &btab[s1 * 8];
  const unsigned short* bb2 = &btab[s2 * 8];

  f32x16 acc0, acc1;
  #pragma unroll
  for (int r = 0; r < 16; ++r) { acc0[r] = bs; acc1[r] = bs; }

  // ---- main loop: per kh = 5 A-reads + 3 B-reads + 6 MFMA, all imm-addressed ----
  __builtin_amdgcn_s_setprio(1);
  #pragma unroll
  for (int kh = 0; kh < KH; ++kh) {
    const unsigned short* ar = abase + kh * LSTR;
    const bf16x8 a0 = *(const bf16x8*)(ar + 0);
    const bf16x8 a1 = *(const bf16x8*)(ar + 16);
    const bf16x8 a2 = *(const bf16x8*)(ar + 32);
    const bf16x8 a3 = *(const bf16x8*)(ar + 48);
    const bf16x8 a4 = *(const bf16x8*)(ar + 64);
    const bf16x8 b0 = *(const bf16x8*)(bb0 + kh * BKH);
    const bf16x8 b1 = *(const bf16x8*)(bb1 + kh * BKH);
    const bf16x8 b2 = *(const bf16x8*)(bb2 + kh * BKH);
    acc0 = MFMA32(a0, b0, acc0);
    acc0 = MFMA32(a1, b1, acc0);
    acc0 = MFMA32(a2, b2, acc0);
    acc1 = MFMA32(a2, b0, acc1);
    acc1 = MFMA32(a3, b1, acc1);
    acc1 = MFMA32(a4, b2, acc1);
  }
  __builtin_amdgcn_s_setprio(0);

  // ---- epilogue: 32x32 C/D layout col = lane&31, row = (reg&3) + 8*(reg>>2) + 4*kg ----
  const int oc  = col0 + 64 * p + n;
  const int orb = row0 + 32 * g + 4 * kg;
  #pragma unroll
  for (int r = 0; r < 16; ++r) {
    const int orow = orb + (r & 3) + 8 * (r >> 2);
    if (orow < HO) {
      if (oc < WO)      out[(long)orow * WO + oc]      = acc0[r];
      if (oc + 32 < WO) out[(long)orow * WO + oc + 32] = acc1[r];
    }
  }
}

extern "C" void kernel_launch(void* const* d_in, const int* in_sizes, int n_in,
                              void* d_out, int out_size, void* d_ws, size_t ws_size,
                              hipStream_t stream) {
  const float* x    = (const float*)d_in[0];
  const float* w    = (const float*)d_in[1];
  const float* bias = (const float*)d_in[2];
  float* out        = (float*)d_out;

  dim3 grid(32, 32);   // 1024 blocks, 128x128 tiles
  conv2d_w32b<<<grid, dim3(512, 1, 1), 0, stream>>>(x, w, bias, out);
}